// Round 21
// baseline (169.120 us; speedup 1.0000x reference)
//
#include <hip/hip_runtime.h>

typedef unsigned int uint32;
typedef unsigned short u16t;
typedef float f4u __attribute__((ext_vector_type(4), aligned(4)));
typedef uint32 u2u __attribute__((ext_vector_type(2), aligned(4)));

// ============================================================
// Compile-time reproduction of np.random.RandomState(0).randn
// (MT19937 + polar Box-Muller). Exact integer/IEEE-double control
// flow -> constexpr-safe; only log/sqrt evaluated on device.
// ============================================================
struct MTS { unsigned int mt[624]; int mti; };

constexpr unsigned int mt_next(MTS& s){
  if (s.mti >= 624){
    for (int i = 0; i < 624; i++){
      unsigned int y = (s.mt[i] & 0x80000000u) | (s.mt[(i+1)%624] & 0x7fffffffu);
      unsigned int v = s.mt[(i+397)%624] ^ (y >> 1);
      if (y & 1u) v ^= 2567483615u;
      s.mt[i] = v;
    }
    s.mti = 0;
  }
  unsigned int y = s.mt[s.mti]; s.mti++;
  y ^= y >> 11;
  y ^= (y << 7)  & 2636928640u;
  y ^= (y << 15) & 4022730752u;
  y ^= y >> 18;
  return y;
}
constexpr double mt_dbl(MTS& s){
  unsigned int a = mt_next(s) >> 5;
  unsigned int b = mt_next(s) >> 6;
  return ((double)a * 67108864.0 + (double)b) / 9007199254740992.0;
}

constexpr int NPAIR = 308;
struct GenData {
  double r2[NPAIR], x1[NPAIR], x2[NPAIR];
  int g_of_t[729];
};

constexpr GenData make_gen(){
  GenData g{};
  for (int i = 0; i < 729; i++) g.g_of_t[i] = -1;
  MTS s{};
  {
    unsigned int sd = 0u;
    for (int p = 0; p < 624; p++){
      s.mt[p] = sd;
      sd = 1812433253u * (sd ^ (sd >> 30)) + (unsigned)p + 1u;
    }
    s.mti = 624;
  }
  for (int p = 0; p < NPAIR; p++){
    double a = 0.0, b = 0.0, r = 0.0;
    do {
      a = 2.0 * mt_dbl(s) - 1.0;
      b = 2.0 * mt_dbl(s) - 1.0;
      r = a*a + b*b;
    } while (r >= 1.0 || r == 0.0);
    g.r2[p] = r; g.x1[p] = a; g.x2[p] = b;
  }
  const int L1[15] = {0,0,0,1,1,1,1,1,1,2,2,2,2,2,2};
  const int L2[15] = {0,1,2,0,1,1,1,2,2,0,1,1,2,2,2};
  const int L3[15] = {0,1,2,1,0,1,2,1,2,2,1,2,0,1,2};
  const int OFF[3] = {0,1,4};
  int gi = 0;
  for (int p = 0; p < 15; p++){
    int d1 = 2*L1[p]+1, d2 = 2*L2[p]+1, d3 = 2*L3[p]+1;
    for (int i = 0; i < d1; i++)
      for (int j = 0; j < d2; j++)
        for (int k = 0; k < d3; k++)
          g.g_of_t[(OFF[L1[p]]+i)*81 + (OFF[L2[p]]+j)*9 + (OFF[L3[p]]+k)] = gi++;
  }
  return g;
}

constexpr GenData h_gd = make_gen();
__constant__ GenData c_gd = h_gd;

// ---- fp32 -> bf16 (RNE) ----
__device__ __forceinline__ u16t f2b(float f){
  uint32 u = __float_as_uint(f);
  u += 0x7fffu + ((u >> 16) & 1u);
  return (u16t)(u >> 16);
}

// standalone gen_T (fallback path only)
__global__ __launch_bounds__(256) void gen_T_kernel(float* __restrict__ T){
  int t = blockIdx.x * blockDim.x + threadIdx.x;
  if (t >= 729) return;
  int gi = c_gd.g_of_t[t];
  float v = 0.f;
  if (gi >= 0){
    int p = gi >> 1;
    double r2 = c_gd.r2[p];
    double f  = sqrt(-2.0 * log(r2) / r2);
    double xx = (gi & 1) ? c_gd.x1[p] : c_gd.x2[p];
    v = (float)((f * xx) / 3.0);
  }
  T[t] = v;
}

// ============================================================
// Fused prep kernel (one launch): gen_T + x repack + hist.
// cnt[] (+ alloc counter) zeroed beforehand by hipMemsetAsync.
// ============================================================
__global__ __launch_bounds__(256) void prep_kernel(
    float* __restrict__ T, const float* __restrict__ x,
    uint32* __restrict__ xb2, const int* __restrict__ dst,
    int* __restrict__ cnt, int* __restrict__ pos, int N, int E){
  int t = blockIdx.x * 256 + threadIdx.x;
  if (t < 729){
    int gi = c_gd.g_of_t[t];
    float v = 0.f;
    if (gi >= 0){
      int p = gi >> 1;
      double r2 = c_gd.r2[p];
      double f  = sqrt(-2.0 * log(r2) / r2);
      double xx = (gi & 1) ? c_gd.x1[p] : c_gd.x2[p];
      v = (float)((f * xx) / 3.0);
    }
    T[t] = v;
  }
  if (t < E) pos[t] = atomicAdd(&cnt[dst[t]], 1);
  if (t >= N * 64) return;
  const int n = t >> 6, c = t & 63;
  const float* xr = x + (size_t)n * 576;
  float v[9];
  v[0] = xr[c];
#pragma unroll
  for (int q = 0; q < 3; q++) v[1 + q] = xr[64 + 3*c + q];
#pragma unroll
  for (int q = 0; q < 5; q++) v[4 + q] = xr[256 + 5*c + q];
  uint32* d = xb2 + (size_t)n * 320 + c * 5;
  d[0] = (uint32)f2b(v[0]) | ((uint32)f2b(v[1]) << 16);
  d[1] = (uint32)f2b(v[2]) | ((uint32)f2b(v[3]) << 16);
  d[2] = (uint32)f2b(v[4]) | ((uint32)f2b(v[5]) << 16);
  d[3] = (uint32)f2b(v[6]) | ((uint32)f2b(v[7]) << 16);
  d[4] = (uint32)f2b(v[8]);
}

// ============================================================
// Parallel segment allocator: start[n] = atomicAdd(counter, cnt[n]).
// ============================================================
__global__ __launch_bounds__(256) void alloc_kernel(const int* __restrict__ cnt,
                                                    int* __restrict__ start,
                                                    int* __restrict__ counter, int n){
  int t = blockIdx.x * 256 + threadIdx.x;
  if (t < n) start[t] = atomicAdd(counter, cnt[t]);
}

__global__ __launch_bounds__(256) void fill_kernel(const int* __restrict__ dst,
                                                   const int* __restrict__ src,
                                                   const int* __restrict__ start,
                                                   const int* __restrict__ pos,
                                                   uint2* __restrict__ epair, int E){
  int e = blockIdx.x * 256 + threadIdx.x;
  if (e >= E) return;
  int p = start[dst[e]] + pos[e];
  epair[p] = make_uint2((uint32)src[e], (uint32)e);
}

// ============================================================
// Split-Z fused TP kernel: 6-edge unrolled ping-pong with
// x TRIPLE-buffered (consume distance 3 blocks) and sh
// DOUBLE-buffered (distance 2 blocks) -> 9 fewer registers
// than R13/R16, frame ~92-96 -> 5 waves/SIMD. Zero rotation
// movs; scalar pairs 7-deep in SGPRs. Same instruction count.
// Block = 256 thr = 2 nodes x 2 half-waves. lane = channel.
// half 0: z[i=0..3][j] (36); half 1: z[i=4..8][j] (45).
// ============================================================
__device__ __forceinline__ int rfl(uint32 v){
  return __builtin_amdgcn_readfirstlane((int)v);
}

template<int HALF>
__device__ __forceinline__ void load_x(const uint32* __restrict__ xb2, int sn, int lane,
                                       uint32 (&xa)[3]){
  constexpr int DW0 = HALF ? 2 : 0;
  const uint32* xp = xb2 + (size_t)sn * 320 + lane * 5 + DW0;
  u2u a = *reinterpret_cast<const u2u*>(xp);
  xa[0] = a[0]; xa[1] = a[1];
  if (HALF) xa[2] = xp[2]; else xa[2] = 0;
}

__device__ __forceinline__ void load_sh(const float* __restrict__ sh, int e, float (&sv)[9]){
  const float* sp = sh + (size_t)e * 9;
  f4u a = *reinterpret_cast<const f4u*>(sp);
  f4u b = *reinterpret_cast<const f4u*>(sp + 4);
  float c = sp[8];
  sv[0]=a[0]; sv[1]=a[1]; sv[2]=a[2]; sv[3]=a[3];
  sv[4]=b[0]; sv[5]=b[1]; sv[6]=b[2]; sv[7]=b[3];
  sv[8]=c;
}

template<int HALF>
__device__ __forceinline__ void accum_half(
    const uint32* __restrict__ xb2, const float* __restrict__ sh,
    const uint2* __restrict__ epair, int s0, int s1, int lane, float (&z)[45])
{
  constexpr int IB  = HALF ? 4 : 0;
  constexpr int IC  = HALF ? 5 : 4;
  constexpr int DW0 = HALF ? 2 : 0;

  if (s0 >= s1) return;
  const int last = s1 - 1;

  auto fma_block = [&](const uint32 (&xa)[3], const float (&sv)[9]){
#pragma unroll
    for (int li = 0; li < IC; ++li){
      const int v = IB + li;
      const uint32 d = xa[(v >> 1) - DW0];
      const float xi = (v & 1) ? __uint_as_float(d & 0xffff0000u)
                               : __uint_as_float(d << 16);
#pragma unroll
      for (int j = 0; j < 9; ++j)
        z[li*9 + j] = fmaf(xi, sv[j], z[li*9 + j]);
    }
  };
  auto clampi = [&](int v){ return (v <= last) ? v : last; };

  // ---- prologue: edges i..i+2 x-loaded, sh for i,i+1 loaded;
  //      scalar pairs held for edges i+2..i+8
  uint2 p;
  p = epair[s0];           const int snI0 = rfl(p.x), enI0 = rfl(p.y);
  p = epair[clampi(s0+1)]; const int snI1 = rfl(p.x), enI1 = rfl(p.y);
  p = epair[clampi(s0+2)]; int sn2 = rfl(p.x), en2 = rfl(p.y);
  p = epair[clampi(s0+3)]; int sn3 = rfl(p.x), en3 = rfl(p.y);
  p = epair[clampi(s0+4)]; int sn4 = rfl(p.x), en4 = rfl(p.y);
  p = epair[clampi(s0+5)]; int sn5 = rfl(p.x), en5 = rfl(p.y);
  p = epair[clampi(s0+6)]; int sn6 = rfl(p.x), en6 = rfl(p.y);
  p = epair[clampi(s0+7)]; int sn7 = rfl(p.x), en7 = rfl(p.y);
  p = epair[clampi(s0+8)]; int sn8 = rfl(p.x), en8 = rfl(p.y);

  uint32 xA[3], xB[3], xC[3];
  float shP[9], shQ[9];
  load_x<HALF>(xb2, snI0, lane, xA);  load_sh(sh, enI0, shP);
  load_x<HALF>(xb2, snI1, lane, xB);  load_sh(sh, enI1, shQ);
  load_x<HALF>(xb2, sn2,  lane, xC);

  int i = s0;
  // invariant at loop top: xA=x(i), xB=x(i+1), xC=x(i+2),
  //                        shP=sh(i), shQ=sh(i+1)
  while (i + 5 < s1){
    // ---- scalar pipeline: pairs for edges i+9..i+14
    p = epair[clampi(i + 9)];  const int sn9  = rfl(p.x), en9  = rfl(p.y);
    p = epair[clampi(i + 10)]; const int sn10 = rfl(p.x), en10 = rfl(p.y);
    p = epair[clampi(i + 11)]; const int sn11 = rfl(p.x), en11 = rfl(p.y);
    p = epair[clampi(i + 12)]; const int sn12 = rfl(p.x), en12 = rfl(p.y);
    p = epair[clampi(i + 13)]; const int sn13 = rfl(p.x), en13 = rfl(p.y);
    p = epair[clampi(i + 14)]; const int sn14 = rfl(p.x), en14 = rfl(p.y);

    // b0: edge i     (x dist 3, sh dist 2)
    fma_block(xA, shP);
    load_x<HALF>(xb2, sn3, lane, xA);  load_sh(sh, en2, shP);
    // b1: edge i+1
    fma_block(xB, shQ);
    load_x<HALF>(xb2, sn4, lane, xB);  load_sh(sh, en3, shQ);
    // b2: edge i+2
    fma_block(xC, shP);
    load_x<HALF>(xb2, sn5, lane, xC);  load_sh(sh, en4, shP);
    // b3: edge i+3
    fma_block(xA, shQ);
    load_x<HALF>(xb2, sn6, lane, xA);  load_sh(sh, en5, shQ);
    // b4: edge i+4
    fma_block(xB, shP);
    load_x<HALF>(xb2, sn7, lane, xB);  load_sh(sh, en6, shP);
    // b5: edge i+5
    fma_block(xC, shQ);
    load_x<HALF>(xb2, sn8, lane, xC);  load_sh(sh, en7, shQ);

    // ---- rotate scalar slots (SALU only): new window i+8..i+14
    sn2 = sn8;  en2 = en8;
    sn3 = sn9;  en3 = en9;
    sn4 = sn10; en4 = en10;
    sn5 = sn11; en5 = en11;
    sn6 = sn12; en6 = en12;
    sn7 = sn13; en7 = en13;
    sn8 = sn14; en8 = en14;
    i += 6;
  }

  // ---- tail: 0..5 edges; buffers hold x(i), x(i+1), x(i+2),
  //      shP=sh(i), shQ=sh(i+1); scalars i+2..i+4 available
  if (i < s1)     fma_block(xA, shP);
  if (i + 1 < s1) fma_block(xB, shQ);
  if (i + 2 < s1){ load_sh(sh, en2, shP); fma_block(xC, shP); }
  if (i + 3 < s1){ load_x<HALF>(xb2, sn3, lane, xA); load_sh(sh, en3, shQ); fma_block(xA, shQ); }
  if (i + 4 < s1){ load_x<HALF>(xb2, sn4, lane, xB); load_sh(sh, en4, shP); fma_block(xB, shP); }
}

template<int HALF>
__device__ __forceinline__ void epilogue_half(const float* __restrict__ Tl,
                                              const float (&z)[45], float (&o)[9])
{
  constexpr int IB = HALF ? 4 : 0;
  constexpr int IC = HALF ? 5 : 4;
#pragma unroll
  for (int m = 0; m < IC * 9; ++m){
    const int t = IB * 9 + m;
    const float4 wa = *reinterpret_cast<const float4*>(&Tl[t*12]);
    const float4 wb = *reinterpret_cast<const float4*>(&Tl[t*12 + 4]);
    const float  w8 = Tl[t*12 + 8];
    const float  zt = z[m];
    o[0] = fmaf(zt, wa.x, o[0]);
    o[1] = fmaf(zt, wa.y, o[1]);
    o[2] = fmaf(zt, wa.z, o[2]);
    o[3] = fmaf(zt, wa.w, o[3]);
    o[4] = fmaf(zt, wb.x, o[4]);
    o[5] = fmaf(zt, wb.y, o[5]);
    o[6] = fmaf(zt, wb.z, o[6]);
    o[7] = fmaf(zt, wb.w, o[7]);
    o[8] = fmaf(zt, w8,   o[8]);
  }
}

__global__ __launch_bounds__(256, 5) void tp_fused(
    const uint32* __restrict__ xb2, const float* __restrict__ sh,
    const uint2* __restrict__ epair, const int* __restrict__ starts,
    const int* __restrict__ cnt, const float* __restrict__ Tg,
    float* __restrict__ out, int n_nodes)
{
  __shared__ __align__(16) float Tl[81 * 12];      // T rows padded to 12 floats
  __shared__ __align__(16) float red[2][64 * 13];  // stride 13: conflict-free

  for (int s = threadIdx.x; s < 81 * 12; s += 256){
    const int t = s / 12, k = s % 12;
    Tl[s] = (k < 9) ? Tg[t * 9 + k] : 0.f;
  }
  __syncthreads();

  const int wv   = threadIdx.x >> 6;
  const int lane = threadIdx.x & 63;
  const int nib  = wv >> 1;       // node within block (0/1)
  const int half = wv & 1;        // i-split half
  int node = blockIdx.x * 2 + nib;
  if (node >= n_nodes) node = n_nodes - 1;   // clamp; keep barrier participation

  const int s0 = rfl((uint32)starts[node]);
  const int s1 = s0 + rfl((uint32)cnt[node]);

  float z[45];
#pragma unroll
  for (int t = 0; t < 45; t++) z[t] = 0.f;

  float o[9];
#pragma unroll
  for (int k = 0; k < 9; k++) o[k] = 0.f;

  if (half == 0){
    accum_half<0>(xb2, sh, epair, s0, s1, lane, z);
    epilogue_half<0>(Tl, z, o);
    float* rp = &red[nib][lane * 13];
    *reinterpret_cast<float4*>(rp)     = make_float4(o[0], o[1], o[2], o[3]);
    *reinterpret_cast<float4*>(rp + 4) = make_float4(o[4], o[5], o[6], o[7]);
    rp[8] = o[8];
  } else {
    accum_half<1>(xb2, sh, epair, s0, s1, lane, z);
    epilogue_half<1>(Tl, z, o);
  }

  __syncthreads();

  if (half == 1){
    const float* rp = &red[nib][lane * 13];
    const float4 ra = *reinterpret_cast<const float4*>(rp);
    const float4 rb = *reinterpret_cast<const float4*>(rp + 4);
    const float  r8 = rp[8];
    o[0] += ra.x; o[1] += ra.y; o[2] += ra.z; o[3] += ra.w;
    o[4] += rb.x; o[5] += rb.y; o[6] += rb.z; o[7] += rb.w;
    o[8] += r8;

    float* orow = out + (size_t)node * 576;
    orow[lane] = o[0];
#pragma unroll
    for (int t = 0; t < 3; t++) orow[64 + 3*lane + t] = o[1 + t];
#pragma unroll
    for (int t = 0; t < 5; t++) orow[256 + 5*lane + t] = o[4 + t];
  }
}

// ============================================================
// Last-resort fallback: edge-parallel with atomics (readlane bcast)
// ============================================================
__device__ __forceinline__ float bcast_lane(float v, int lane){
  return __uint_as_float(__builtin_amdgcn_readlane(__float_as_uint(v), lane));
}

__global__ __launch_bounds__(256) void tp_edge_atomic(
    const float* __restrict__ x, const float* __restrict__ sh,
    const int* __restrict__ src, const int* __restrict__ dst,
    const float* __restrict__ Tg, float* __restrict__ out, int E)
{
  const int wv = threadIdx.x >> 6;
  const int lane = threadIdx.x & 63;
  const int e = blockIdx.x * 4 + wv;
  if (e >= E) return;

  const int i0 = lane / 9, k0 = lane % 9;
  const bool has1 = (lane < 17);
  const int e1 = has1 ? (64 + lane) : 63;
  const int i1 = e1 / 9, k1 = e1 % 9;
  float t0[9], t1[9];
#pragma unroll
  for (int j = 0; j < 9; j++){
    t0[j] = Tg[i0*81 + j*9 + k0];
    t1[j] = Tg[i1*81 + j*9 + k1];
  }

  const int sn = src[e];
  const float* she = sh + (size_t)e * 9;
  float sv[9];
#pragma unroll
  for (int j = 0; j < 9; j++) sv[j] = she[j];

  float w0 = 0.f, w1 = 0.f;
#pragma unroll
  for (int j = 0; j < 9; j++) w0 = fmaf(sv[j], t0[j], w0);
#pragma unroll
  for (int j = 0; j < 9; j++) w1 = fmaf(sv[j], t1[j], w1);

  const float* xr = x + (size_t)sn * 576;
  float xv[9];
  xv[0] = xr[lane];
#pragma unroll
  for (int t = 0; t < 3; t++) xv[1 + t] = xr[64 + 3*lane + t];
#pragma unroll
  for (int t = 0; t < 5; t++) xv[4 + t] = xr[256 + 5*lane + t];

  float o[9];
#pragma unroll
  for (int k = 0; k < 9; k++) o[k] = 0.f;
#pragma unroll
  for (int i = 0; i < 9; i++){
    const float xi = xv[i];
#pragma unroll
    for (int k = 0; k < 9; k++){
      const int t = i*9 + k;
      const float w = (t < 64) ? bcast_lane(w0, t) : bcast_lane(w1, t - 64);
      o[k] = fmaf(xi, w, o[k]);
    }
  }

  float* orow = out + (size_t)dst[e] * 576;
  atomicAdd(&orow[lane], o[0]);
#pragma unroll
  for (int t = 0; t < 3; t++) atomicAdd(&orow[64 + 3*lane + t], o[1 + t]);
#pragma unroll
  for (int t = 0; t < 5; t++) atomicAdd(&orow[256 + 5*lane + t], o[4 + t]);
}

// ============================================================
extern "C" void kernel_launch(void* const* d_in, const int* in_sizes, int n_in,
                              void* d_out, int out_size, void* d_ws, size_t ws_size,
                              hipStream_t stream)
{
  const float* x  = (const float*)d_in[0];
  const float* sh = (const float*)d_in[1];
  const int* src  = (const int*)d_in[2];
  const int* dst  = (const int*)d_in[3];
  float* out = (float*)d_out;

  const int N = in_sizes[0] / 576;
  const int E = in_sizes[2];

  // layout (u32 units):
  // Tw[1024] | cnt[N] | counter[1] | strt[N] | pos[E] | epair[2E] | xb2[320N]
  const size_t o_cnt  = 1024;
  const size_t o_ctr  = o_cnt + (size_t)N;
  const size_t o_strt = o_ctr + 1;
  const size_t o_pos  = o_strt + (size_t)N;
  size_t o_ep   = o_pos + (size_t)E;
  o_ep = (o_ep + 1) & ~(size_t)1;              // 8B-align epair
  size_t o_xb   = o_ep + (size_t)2 * E;
  o_xb = (o_xb + 3) & ~(size_t)3;              // 16B-align xb2
  const size_t need = (o_xb + (size_t)320 * N) * 4;

  float* Tw = (float*)d_ws;

  if (ws_size >= need){
    int* cnt    = (int*)d_ws + o_cnt;
    int* ctr    = (int*)d_ws + o_ctr;
    int* strt   = (int*)d_ws + o_strt;
    int* pos    = (int*)d_ws + o_pos;
    uint2* ep   = (uint2*)((uint32*)d_ws + o_ep);
    uint32* xb2 = (uint32*)d_ws + o_xb;

    hipMemsetAsync(cnt, 0, ((size_t)N + 1) * 4, stream);   // cnt + counter
    const int rh = (N * 64 > E ? N * 64 : E);
    prep_kernel<<<(rh + 255) / 256, 256, 0, stream>>>(Tw, x, xb2, dst, cnt, pos, N, E);
    alloc_kernel<<<(N + 255) / 256, 256, 0, stream>>>(cnt, strt, ctr, N);
    fill_kernel<<<(E + 255) / 256, 256, 0, stream>>>(dst, src, strt, pos, ep, E);
    tp_fused<<<(N + 1) / 2, 256, 0, stream>>>(xb2, sh, ep, strt, cnt, Tw, out, N);
  } else {
    gen_T_kernel<<<3, 256, 0, stream>>>(Tw);
    hipMemsetAsync(out, 0, (size_t)out_size * 4, stream);
    tp_edge_atomic<<<(E + 3) / 4, 256, 0, stream>>>(x, sh, src, dst, Tw, out, E);
  }
}

// Round 22
// 133.225 us; speedup vs baseline: 1.2694x; 1.2694x over previous
//
#include <hip/hip_runtime.h>

typedef unsigned int uint32;
typedef unsigned short u16t;
typedef float f4u __attribute__((ext_vector_type(4), aligned(4)));
typedef uint32 u2u __attribute__((ext_vector_type(2), aligned(4)));

// ============================================================
// Compile-time reproduction of np.random.RandomState(0).randn
// (MT19937 + polar Box-Muller). Exact integer/IEEE-double control
// flow -> constexpr-safe; only log/sqrt evaluated on device.
// ============================================================
struct MTS { unsigned int mt[624]; int mti; };

constexpr unsigned int mt_next(MTS& s){
  if (s.mti >= 624){
    for (int i = 0; i < 624; i++){
      unsigned int y = (s.mt[i] & 0x80000000u) | (s.mt[(i+1)%624] & 0x7fffffffu);
      unsigned int v = s.mt[(i+397)%624] ^ (y >> 1);
      if (y & 1u) v ^= 2567483615u;
      s.mt[i] = v;
    }
    s.mti = 0;
  }
  unsigned int y = s.mt[s.mti]; s.mti++;
  y ^= y >> 11;
  y ^= (y << 7)  & 2636928640u;
  y ^= (y << 15) & 4022730752u;
  y ^= y >> 18;
  return y;
}
constexpr double mt_dbl(MTS& s){
  unsigned int a = mt_next(s) >> 5;
  unsigned int b = mt_next(s) >> 6;
  return ((double)a * 67108864.0 + (double)b) / 9007199254740992.0;
}

constexpr int NPAIR = 308;
struct GenData {
  double r2[NPAIR], x1[NPAIR], x2[NPAIR];
  int g_of_t[729];
};

constexpr GenData make_gen(){
  GenData g{};
  for (int i = 0; i < 729; i++) g.g_of_t[i] = -1;
  MTS s{};
  {
    unsigned int sd = 0u;
    for (int p = 0; p < 624; p++){
      s.mt[p] = sd;
      sd = 1812433253u * (sd ^ (sd >> 30)) + (unsigned)p + 1u;
    }
    s.mti = 624;
  }
  for (int p = 0; p < NPAIR; p++){
    double a = 0.0, b = 0.0, r = 0.0;
    do {
      a = 2.0 * mt_dbl(s) - 1.0;
      b = 2.0 * mt_dbl(s) - 1.0;
      r = a*a + b*b;
    } while (r >= 1.0 || r == 0.0);
    g.r2[p] = r; g.x1[p] = a; g.x2[p] = b;
  }
  const int L1[15] = {0,0,0,1,1,1,1,1,1,2,2,2,2,2,2};
  const int L2[15] = {0,1,2,0,1,1,1,2,2,0,1,1,2,2,2};
  const int L3[15] = {0,1,2,1,0,1,2,1,2,2,1,2,0,1,2};
  const int OFF[3] = {0,1,4};
  int gi = 0;
  for (int p = 0; p < 15; p++){
    int d1 = 2*L1[p]+1, d2 = 2*L2[p]+1, d3 = 2*L3[p]+1;
    for (int i = 0; i < d1; i++)
      for (int j = 0; j < d2; j++)
        for (int k = 0; k < d3; k++)
          g.g_of_t[(OFF[L1[p]]+i)*81 + (OFF[L2[p]]+j)*9 + (OFF[L3[p]]+k)] = gi++;
  }
  return g;
}

constexpr GenData h_gd = make_gen();
__constant__ GenData c_gd = h_gd;

// ---- fp32 -> bf16 (RNE) ----
__device__ __forceinline__ u16t f2b(float f){
  uint32 u = __float_as_uint(f);
  u += 0x7fffu + ((u >> 16) & 1u);
  return (u16t)(u >> 16);
}

// standalone gen_T (fallback path only)
__global__ __launch_bounds__(256) void gen_T_kernel(float* __restrict__ T){
  int t = blockIdx.x * blockDim.x + threadIdx.x;
  if (t >= 729) return;
  int gi = c_gd.g_of_t[t];
  float v = 0.f;
  if (gi >= 0){
    int p = gi >> 1;
    double r2 = c_gd.r2[p];
    double f  = sqrt(-2.0 * log(r2) / r2);
    double xx = (gi & 1) ? c_gd.x1[p] : c_gd.x2[p];
    v = (float)((f * xx) / 3.0);
  }
  T[t] = v;
}

// ============================================================
// Fused prep kernel (one launch): gen_T + x repack + hist.
// cnt[] (+ alloc counter) zeroed beforehand by hipMemsetAsync.
//   t < 729  : dense T
//   t < E    : histogram by dst
//   t < N*64 : x repack to per-channel bf16 rows (20B)
// ============================================================
__global__ __launch_bounds__(256) void prep_kernel(
    float* __restrict__ T, const float* __restrict__ x,
    uint32* __restrict__ xb2, const int* __restrict__ dst,
    int* __restrict__ cnt, int* __restrict__ pos, int N, int E){
  int t = blockIdx.x * 256 + threadIdx.x;
  if (t < 729){
    int gi = c_gd.g_of_t[t];
    float v = 0.f;
    if (gi >= 0){
      int p = gi >> 1;
      double r2 = c_gd.r2[p];
      double f  = sqrt(-2.0 * log(r2) / r2);
      double xx = (gi & 1) ? c_gd.x1[p] : c_gd.x2[p];
      v = (float)((f * xx) / 3.0);
    }
    T[t] = v;
  }
  if (t < E) pos[t] = atomicAdd(&cnt[dst[t]], 1);
  if (t >= N * 64) return;
  const int n = t >> 6, c = t & 63;
  const float* xr = x + (size_t)n * 576;
  float v[9];
  v[0] = xr[c];
#pragma unroll
  for (int q = 0; q < 3; q++) v[1 + q] = xr[64 + 3*c + q];
#pragma unroll
  for (int q = 0; q < 5; q++) v[4 + q] = xr[256 + 5*c + q];
  uint32* d = xb2 + (size_t)n * 320 + c * 5;
  d[0] = (uint32)f2b(v[0]) | ((uint32)f2b(v[1]) << 16);
  d[1] = (uint32)f2b(v[2]) | ((uint32)f2b(v[3]) << 16);
  d[2] = (uint32)f2b(v[4]) | ((uint32)f2b(v[5]) << 16);
  d[3] = (uint32)f2b(v[6]) | ((uint32)f2b(v[7]) << 16);
  d[4] = (uint32)f2b(v[8]);
}

// ============================================================
// Parallel segment allocator (replaces serial 1-block scan):
// start[n] = atomicAdd(counter, cnt[n]). Node segments are
// contiguous; global ordering is irrelevant to tp (it uses
// s1 = start[n] + cnt[n]).
// ============================================================
__global__ __launch_bounds__(256) void alloc_kernel(const int* __restrict__ cnt,
                                                    int* __restrict__ start,
                                                    int* __restrict__ counter, int n){
  int t = blockIdx.x * 256 + threadIdx.x;
  if (t < n) start[t] = atomicAdd(counter, cnt[t]);
}

__global__ __launch_bounds__(256) void fill_kernel(const int* __restrict__ dst,
                                                   const int* __restrict__ src,
                                                   const int* __restrict__ start,
                                                   const int* __restrict__ pos,
                                                   uint2* __restrict__ epair, int E){
  int e = blockIdx.x * 256 + threadIdx.x;
  if (e >= E) return;
  int p = start[dst[e]] + pos[e];
  epair[p] = make_uint2((uint32)src[e], (uint32)e);
}

// ============================================================
// Split-Z fused TP kernel (R13 structure — best measured).
// Block = 256 threads = 2 nodes x 2 half-waves. lane = channel.
// half 0: z[i=0..3][j] (36 regs); half 1: z[i=4..8][j] (45 regs).
// Triple-buffer rotation-free pipeline (consume distance = 2
// fma_blocks); buffers reused in place, scalars in SGPRs.
// ============================================================
__device__ __forceinline__ int rfl(uint32 v){
  return __builtin_amdgcn_readfirstlane((int)v);
}

template<int HALF>
__device__ __forceinline__ void load_x(const uint32* __restrict__ xb2, int sn, int lane,
                                       uint32 (&xa)[3]){
  constexpr int DW0 = HALF ? 2 : 0;
  const uint32* xp = xb2 + (size_t)sn * 320 + lane * 5 + DW0;
  u2u a = *reinterpret_cast<const u2u*>(xp);
  xa[0] = a[0]; xa[1] = a[1];
  if (HALF) xa[2] = xp[2]; else xa[2] = 0;
}

__device__ __forceinline__ void load_sh(const float* __restrict__ sh, int e, float (&sv)[9]){
  const float* sp = sh + (size_t)e * 9;
  f4u a = *reinterpret_cast<const f4u*>(sp);
  f4u b = *reinterpret_cast<const f4u*>(sp + 4);
  float c = sp[8];
  sv[0]=a[0]; sv[1]=a[1]; sv[2]=a[2]; sv[3]=a[3];
  sv[4]=b[0]; sv[5]=b[1]; sv[6]=b[2]; sv[7]=b[3];
  sv[8]=c;
}

template<int HALF>
__device__ __forceinline__ void accum_half(
    const uint32* __restrict__ xb2, const float* __restrict__ sh,
    const uint2* __restrict__ epair, int s0, int s1, int lane, float (&z)[45])
{
  constexpr int IB  = HALF ? 4 : 0;
  constexpr int IC  = HALF ? 5 : 4;
  constexpr int DW0 = HALF ? 2 : 0;

  if (s0 >= s1) return;
  const int last = s1 - 1;

  auto fma_block = [&](const uint32 (&xa)[3], const float (&sv)[9]){
#pragma unroll
    for (int li = 0; li < IC; ++li){
      const int v = IB + li;
      const uint32 d = xa[(v >> 1) - DW0];
      const float xi = (v & 1) ? __uint_as_float(d & 0xffff0000u)
                               : __uint_as_float(d << 16);
#pragma unroll
      for (int j = 0; j < 9; ++j)
        z[li*9 + j] = fmaf(xi, sv[j], z[li*9 + j]);
    }
  };
  auto clampi = [&](int v){ return (v <= last) ? v : last; };

  // ---- prologue: edges i..i+2 loaded; scalars for i+3..i+5 resident
  uint2 p;
  p = epair[s0];            const int snA = rfl(p.x), enA = rfl(p.y);
  p = epair[clampi(s0+1)];  const int snB = rfl(p.x), enB = rfl(p.y);
  p = epair[clampi(s0+2)];  const int snC = rfl(p.x), enC = rfl(p.y);
  p = epair[clampi(s0+3)];  int sn3 = rfl(p.x), en3 = rfl(p.y);
  p = epair[clampi(s0+4)];  int sn4 = rfl(p.x), en4 = rfl(p.y);
  p = epair[clampi(s0+5)];  int sn5 = rfl(p.x), en5 = rfl(p.y);

  uint32 xA[3], xB[3], xC[3];
  float shA[9], shB[9], shC[9];
  load_x<HALF>(xb2, snA, lane, xA);  load_sh(sh, enA, shA);
  load_x<HALF>(xb2, snB, lane, xB);  load_sh(sh, enB, shB);
  load_x<HALF>(xb2, snC, lane, xC);  load_sh(sh, enC, shC);

  int i = s0;
  while (i + 2 < s1){
    // ---- fetch scalar pairs for i+6..i+8 (SGPR pipeline)
    p = epair[clampi(i + 6)]; const int sn6 = rfl(p.x), en6 = rfl(p.y);
    p = epair[clampi(i + 7)]; const int sn7 = rfl(p.x), en7 = rfl(p.y);
    p = epair[clampi(i + 8)]; const int sn8 = rfl(p.x), en8 = rfl(p.y);

    // ---- edge i: compute A, reuse A for edge i+3
    fma_block(xA, shA);
    load_x<HALF>(xb2, sn3, lane, xA);  load_sh(sh, en3, shA);
    // ---- edge i+1: compute B, reuse B for edge i+4
    fma_block(xB, shB);
    load_x<HALF>(xb2, sn4, lane, xB);  load_sh(sh, en4, shB);
    // ---- edge i+2: compute C, reuse C for edge i+5
    fma_block(xC, shC);
    load_x<HALF>(xb2, sn5, lane, xC);  load_sh(sh, en5, shC);

    // ---- scalar rotate only (SALU)
    sn3 = sn6; en3 = en6; sn4 = sn7; en4 = en7; sn5 = sn8; en5 = en8;
    i += 3;
  }
  // tail: 0, 1 or 2 edges left; A holds edge i, B holds edge i+1
  if (i < s1)     fma_block(xA, shA);
  if (i + 1 < s1) fma_block(xB, shB);
}

template<int HALF>
__device__ __forceinline__ void epilogue_half(const float* __restrict__ Tl,
                                              const float (&z)[45], float (&o)[9])
{
  constexpr int IB = HALF ? 4 : 0;
  constexpr int IC = HALF ? 5 : 4;
#pragma unroll
  for (int m = 0; m < IC * 9; ++m){
    const int t = IB * 9 + m;
    const float4 wa = *reinterpret_cast<const float4*>(&Tl[t*12]);
    const float4 wb = *reinterpret_cast<const float4*>(&Tl[t*12 + 4]);
    const float  w8 = Tl[t*12 + 8];
    const float  zt = z[m];
    o[0] = fmaf(zt, wa.x, o[0]);
    o[1] = fmaf(zt, wa.y, o[1]);
    o[2] = fmaf(zt, wa.z, o[2]);
    o[3] = fmaf(zt, wa.w, o[3]);
    o[4] = fmaf(zt, wb.x, o[4]);
    o[5] = fmaf(zt, wb.y, o[5]);
    o[6] = fmaf(zt, wb.z, o[6]);
    o[7] = fmaf(zt, wb.w, o[7]);
    o[8] = fmaf(zt, w8,   o[8]);
  }
}

__global__ __launch_bounds__(256, 5) void tp_fused(
    const uint32* __restrict__ xb2, const float* __restrict__ sh,
    const uint2* __restrict__ epair, const int* __restrict__ starts,
    const int* __restrict__ cnt, const float* __restrict__ Tg,
    float* __restrict__ out, int n_nodes)
{
  __shared__ __align__(16) float Tl[81 * 12];      // T rows padded to 12 floats
  __shared__ __align__(16) float red[2][64 * 13];  // stride 13: conflict-free

  for (int s = threadIdx.x; s < 81 * 12; s += 256){
    const int t = s / 12, k = s % 12;
    Tl[s] = (k < 9) ? Tg[t * 9 + k] : 0.f;
  }
  __syncthreads();

  const int wv   = threadIdx.x >> 6;
  const int lane = threadIdx.x & 63;
  const int nib  = wv >> 1;       // node within block (0/1)
  const int half = wv & 1;        // i-split half
  int node = blockIdx.x * 2 + nib;
  if (node >= n_nodes) node = n_nodes - 1;   // clamp; keep barrier participation

  const int s0 = rfl((uint32)starts[node]);
  const int s1 = s0 + rfl((uint32)cnt[node]);

  float z[45];
#pragma unroll
  for (int t = 0; t < 45; t++) z[t] = 0.f;

  float o[9];
#pragma unroll
  for (int k = 0; k < 9; k++) o[k] = 0.f;

  if (half == 0){
    accum_half<0>(xb2, sh, epair, s0, s1, lane, z);
    epilogue_half<0>(Tl, z, o);
    float* rp = &red[nib][lane * 13];
    *reinterpret_cast<float4*>(rp)     = make_float4(o[0], o[1], o[2], o[3]);
    *reinterpret_cast<float4*>(rp + 4) = make_float4(o[4], o[5], o[6], o[7]);
    rp[8] = o[8];
  } else {
    accum_half<1>(xb2, sh, epair, s0, s1, lane, z);
    epilogue_half<1>(Tl, z, o);
  }

  __syncthreads();

  if (half == 1){
    const float* rp = &red[nib][lane * 13];
    const float4 ra = *reinterpret_cast<const float4*>(rp);
    const float4 rb = *reinterpret_cast<const float4*>(rp + 4);
    const float  r8 = rp[8];
    o[0] += ra.x; o[1] += ra.y; o[2] += ra.z; o[3] += ra.w;
    o[4] += rb.x; o[5] += rb.y; o[6] += rb.z; o[7] += rb.w;
    o[8] += r8;

    float* orow = out + (size_t)node * 576;
    orow[lane] = o[0];
#pragma unroll
    for (int t = 0; t < 3; t++) orow[64 + 3*lane + t] = o[1 + t];
#pragma unroll
    for (int t = 0; t < 5; t++) orow[256 + 5*lane + t] = o[4 + t];
  }
}

// ============================================================
// Last-resort fallback: edge-parallel with atomics (readlane bcast)
// ============================================================
__device__ __forceinline__ float bcast_lane(float v, int lane){
  return __uint_as_float(__builtin_amdgcn_readlane(__float_as_uint(v), lane));
}

__global__ __launch_bounds__(256) void tp_edge_atomic(
    const float* __restrict__ x, const float* __restrict__ sh,
    const int* __restrict__ src, const int* __restrict__ dst,
    const float* __restrict__ Tg, float* __restrict__ out, int E)
{
  const int wv = threadIdx.x >> 6;
  const int lane = threadIdx.x & 63;
  const int e = blockIdx.x * 4 + wv;
  if (e >= E) return;

  const int i0 = lane / 9, k0 = lane % 9;
  const bool has1 = (lane < 17);
  const int e1 = has1 ? (64 + lane) : 63;
  const int i1 = e1 / 9, k1 = e1 % 9;
  float t0[9], t1[9];
#pragma unroll
  for (int j = 0; j < 9; j++){
    t0[j] = Tg[i0*81 + j*9 + k0];
    t1[j] = Tg[i1*81 + j*9 + k1];
  }

  const int sn = src[e];
  const float* she = sh + (size_t)e * 9;
  float sv[9];
#pragma unroll
  for (int j = 0; j < 9; j++) sv[j] = she[j];

  float w0 = 0.f, w1 = 0.f;
#pragma unroll
  for (int j = 0; j < 9; j++) w0 = fmaf(sv[j], t0[j], w0);
#pragma unroll
  for (int j = 0; j < 9; j++) w1 = fmaf(sv[j], t1[j], w1);

  const float* xr = x + (size_t)sn * 576;
  float xv[9];
  xv[0] = xr[lane];
#pragma unroll
  for (int t = 0; t < 3; t++) xv[1 + t] = xr[64 + 3*lane + t];
#pragma unroll
  for (int t = 0; t < 5; t++) xv[4 + t] = xr[256 + 5*lane + t];

  float o[9];
#pragma unroll
  for (int k = 0; k < 9; k++) o[k] = 0.f;
#pragma unroll
  for (int i = 0; i < 9; i++){
    const float xi = xv[i];
#pragma unroll
    for (int k = 0; k < 9; k++){
      const int t = i*9 + k;
      const float w = (t < 64) ? bcast_lane(w0, t) : bcast_lane(w1, t - 64);
      o[k] = fmaf(xi, w, o[k]);
    }
  }

  float* orow = out + (size_t)dst[e] * 576;
  atomicAdd(&orow[lane], o[0]);
#pragma unroll
  for (int t = 0; t < 3; t++) atomicAdd(&orow[64 + 3*lane + t], o[1 + t]);
#pragma unroll
  for (int t = 0; t < 5; t++) atomicAdd(&orow[256 + 5*lane + t], o[4 + t]);
}

// ============================================================
extern "C" void kernel_launch(void* const* d_in, const int* in_sizes, int n_in,
                              void* d_out, int out_size, void* d_ws, size_t ws_size,
                              hipStream_t stream)
{
  const float* x  = (const float*)d_in[0];
  const float* sh = (const float*)d_in[1];
  const int* src  = (const int*)d_in[2];
  const int* dst  = (const int*)d_in[3];
  float* out = (float*)d_out;

  const int N = in_sizes[0] / 576;
  const int E = in_sizes[2];

  // layout (u32 units):
  // Tw[1024] | cnt[N] | counter[1] | strt[N] | pos[E] | epair[2E] | xb2[320N]
  const size_t o_cnt  = 1024;
  const size_t o_ctr  = o_cnt + (size_t)N;
  const size_t o_strt = o_ctr + 1;
  const size_t o_pos  = o_strt + (size_t)N;
  size_t o_ep   = o_pos + (size_t)E;
  o_ep = (o_ep + 1) & ~(size_t)1;              // 8B-align epair
  size_t o_xb   = o_ep + (size_t)2 * E;
  o_xb = (o_xb + 3) & ~(size_t)3;              // 16B-align xb2
  const size_t need = (o_xb + (size_t)320 * N) * 4;

  float* Tw = (float*)d_ws;

  if (ws_size >= need){
    int* cnt    = (int*)d_ws + o_cnt;
    int* ctr    = (int*)d_ws + o_ctr;
    int* strt   = (int*)d_ws + o_strt;
    int* pos    = (int*)d_ws + o_pos;
    uint2* ep   = (uint2*)((uint32*)d_ws + o_ep);
    uint32* xb2 = (uint32*)d_ws + o_xb;

    hipMemsetAsync(cnt, 0, ((size_t)N + 1) * 4, stream);   // cnt + counter
    const int rh = (N * 64 > E ? N * 64 : E);
    prep_kernel<<<(rh + 255) / 256, 256, 0, stream>>>(Tw, x, xb2, dst, cnt, pos, N, E);
    alloc_kernel<<<(N + 255) / 256, 256, 0, stream>>>(cnt, strt, ctr, N);
    fill_kernel<<<(E + 255) / 256, 256, 0, stream>>>(dst, src, strt, pos, ep, E);
    tp_fused<<<(N + 1) / 2, 256, 0, stream>>>(xb2, sh, ep, strt, cnt, Tw, out, N);
  } else {
    gen_T_kernel<<<3, 256, 0, stream>>>(Tw);
    hipMemsetAsync(out, 0, (size_t)out_size * 4, stream);
    tp_edge_atomic<<<(E + 3) / 4, 256, 0, stream>>>(x, sh, src, dst, Tw, out, E);
  }
}